// Round 4
// baseline (1519.417 us; speedup 1.0000x reference)
//
#include <hip/hip_runtime.h>
#include <math.h>

#define THREADS 256

// ---------------- degree ----------------
__global__ __launch_bounds__(THREADS) void k_deg(const int* __restrict__ dst,
                                                 float* __restrict__ deg, int E) {
    int e = blockIdx.x * THREADS + threadIdx.x;
    if (e < E) atomicAdd(&deg[dst[e]], 1.0f);
}

__global__ __launch_bounds__(THREADS) void k_dinv(const float* __restrict__ deg,
                                                  float* __restrict__ dinv, int n) {
    int v = blockIdx.x * THREADS + threadIdx.x;
    if (v < n) dinv[v] = rsqrtf(deg[v] + 1.0f);  // +1 for self-loop
}

// ---------------- layer-1 GEMM: hs = (x @ W1) * dinv ; agg1 init = hs (self-loop) ----
// 16 lanes per row-group, 4 rows per group, W1^T staged in LDS (padded to 516).
__global__ __launch_bounds__(THREADS) void k_gemm1(const float* __restrict__ x,
                                                   const float* __restrict__ W1,
                                                   const float* __restrict__ dinv,
                                                   float* __restrict__ hs,
                                                   float* __restrict__ agg1, int n) {
    __shared__ float wt[16][516];  // wt[j][k] = W1[k][j]; pad 516 -> 2-way max bank alias
    for (int idx = threadIdx.x; idx < 512 * 16; idx += THREADS) {
        int k = idx >> 4, j = idx & 15;
        wt[j][k] = W1[idx];
    }
    __syncthreads();

    const int g = threadIdx.x >> 4;   // group 0..15 within block
    const int j = threadIdx.x & 15;   // output column
    const int base = blockIdx.x * 64 + g * 4;
    if (base >= n && blockIdx.x * 64 >= n) return;  // fully-past-end block guard

    int r0 = min(base + 0, n - 1);
    int r1 = min(base + 1, n - 1);
    int r2 = min(base + 2, n - 1);
    int r3 = min(base + 3, n - 1);

    const float4* __restrict__ x0 = (const float4*)(x + (size_t)r0 * 512);
    const float4* __restrict__ x1 = (const float4*)(x + (size_t)r1 * 512);
    const float4* __restrict__ x2 = (const float4*)(x + (size_t)r2 * 512);
    const float4* __restrict__ x3 = (const float4*)(x + (size_t)r3 * 512);
    const float4* __restrict__ w4 = (const float4*)(&wt[j][0]);  // j*2064 B, 16B-aligned

    float a0 = 0.f, a1 = 0.f, a2 = 0.f, a3 = 0.f;
#pragma unroll 4
    for (int k4 = 0; k4 < 128; ++k4) {
        float4 w = w4[k4];
        float4 v;
        v = x0[k4];
        a0 = fmaf(v.x, w.x, a0); a0 = fmaf(v.y, w.y, a0);
        a0 = fmaf(v.z, w.z, a0); a0 = fmaf(v.w, w.w, a0);
        v = x1[k4];
        a1 = fmaf(v.x, w.x, a1); a1 = fmaf(v.y, w.y, a1);
        a1 = fmaf(v.z, w.z, a1); a1 = fmaf(v.w, w.w, a1);
        v = x2[k4];
        a2 = fmaf(v.x, w.x, a2); a2 = fmaf(v.y, w.y, a2);
        a2 = fmaf(v.z, w.z, a2); a2 = fmaf(v.w, w.w, a2);
        v = x3[k4];
        a3 = fmaf(v.x, w.x, a3); a3 = fmaf(v.y, w.y, a3);
        a3 = fmaf(v.z, w.z, a3); a3 = fmaf(v.w, w.w, a3);
    }

    if (base + 0 < n) { float h = a0 * dinv[r0]; hs[(size_t)r0 * 16 + j] = h; agg1[(size_t)r0 * 16 + j] = h; }
    if (base + 1 < n) { float h = a1 * dinv[r1]; hs[(size_t)r1 * 16 + j] = h; agg1[(size_t)r1 * 16 + j] = h; }
    if (base + 2 < n) { float h = a2 * dinv[r2]; hs[(size_t)r2 * 16 + j] = h; agg1[(size_t)r2 * 16 + j] = h; }
    if (base + 3 < n) { float h = a3 * dinv[r3]; hs[(size_t)r3 * 16 + j] = h; agg1[(size_t)r3 * 16 + j] = h; }
}

// ---------------- scatter-add layer 1: agg1[dst] += hs[src] (16 feats, 4 threads/edge) ----
__global__ __launch_bounds__(THREADS) void k_scatter1(const int* __restrict__ src,
                                                      const int* __restrict__ dst,
                                                      const float* __restrict__ hs,
                                                      float* __restrict__ agg1, int E) {
    int t = blockIdx.x * THREADS + threadIdx.x;
    if (t >= 4 * E) return;
    int e = t >> 2, q = t & 3;
    int s = src[e], d = dst[e];
    float4 v = ((const float4*)hs)[(size_t)s * 4 + q];
    float* o = agg1 + (size_t)d * 16 + q * 4;
    atomicAdd(o + 0, v.x);
    atomicAdd(o + 1, v.y);
    atomicAdd(o + 2, v.z);
    atomicAdd(o + 3, v.w);
}

// ---------------- layer-2: h1 = relu(dinv*agg1 + b1); hs2 = (h1@W2)*dinv; agg2 init ----
__global__ __launch_bounds__(THREADS) void k_layer2(const float* __restrict__ agg1,
                                                    const float* __restrict__ dinv,
                                                    const float* __restrict__ b1,
                                                    const float* __restrict__ W2,
                                                    float* __restrict__ hs2,
                                                    float* __restrict__ agg2, int n) {
    int v = blockIdx.x * THREADS + threadIdx.x;
    if (v >= n) return;
    float dv = dinv[v];
    const float4* ag = (const float4*)(agg1 + (size_t)v * 16);
    float c0 = 0.f, c1 = 0.f;
#pragma unroll
    for (int jq = 0; jq < 4; ++jq) {
        float4 a = ag[jq];
        float h;
        h = fmaxf(fmaf(dv, a.x, b1[jq * 4 + 0]), 0.f);
        c0 = fmaf(h, W2[(jq * 4 + 0) * 2 + 0], c0); c1 = fmaf(h, W2[(jq * 4 + 0) * 2 + 1], c1);
        h = fmaxf(fmaf(dv, a.y, b1[jq * 4 + 1]), 0.f);
        c0 = fmaf(h, W2[(jq * 4 + 1) * 2 + 0], c0); c1 = fmaf(h, W2[(jq * 4 + 1) * 2 + 1], c1);
        h = fmaxf(fmaf(dv, a.z, b1[jq * 4 + 2]), 0.f);
        c0 = fmaf(h, W2[(jq * 4 + 2) * 2 + 0], c0); c1 = fmaf(h, W2[(jq * 4 + 2) * 2 + 1], c1);
        h = fmaxf(fmaf(dv, a.w, b1[jq * 4 + 3]), 0.f);
        c0 = fmaf(h, W2[(jq * 4 + 3) * 2 + 0], c0); c1 = fmaf(h, W2[(jq * 4 + 3) * 2 + 1], c1);
    }
    float o0 = c0 * dv, o1 = c1 * dv;
    ((float2*)hs2)[v] = make_float2(o0, o1);
    ((float2*)agg2)[v] = make_float2(o0, o1);
}

// ---------------- scatter-add layer 2: agg2[dst] += hs2[src] (2 feats) ----
__global__ __launch_bounds__(THREADS) void k_scatter2(const int* __restrict__ src,
                                                      const int* __restrict__ dst,
                                                      const float* __restrict__ hs2,
                                                      float* __restrict__ agg2, int E) {
    int e = blockIdx.x * THREADS + threadIdx.x;
    if (e >= E) return;
    int s = src[e], d = dst[e];
    float2 v = ((const float2*)hs2)[s];
    atomicAdd(&agg2[(size_t)d * 2 + 0], v.x);
    atomicAdd(&agg2[(size_t)d * 2 + 1], v.y);
}

// ---------------- final: out = sigmoid(dinv*agg2 + b2) ----
__global__ __launch_bounds__(THREADS) void k_final(const float* __restrict__ agg2,
                                                   const float* __restrict__ dinv,
                                                   const float* __restrict__ b2,
                                                   float* __restrict__ out, int n) {
    int v = blockIdx.x * THREADS + threadIdx.x;
    if (v >= n) return;
    float dv = dinv[v];
    float2 a = ((const float2*)agg2)[v];
    float z0 = fmaf(dv, a.x, b2[0]);
    float z1 = fmaf(dv, a.y, b2[1]);
    float o0 = 1.0f / (1.0f + expf(-z0));
    float o1 = 1.0f / (1.0f + expf(-z1));
    ((float2*)out)[v] = make_float2(o0, o1);
}

extern "C" void kernel_launch(void* const* d_in, const int* in_sizes, int n_in,
                              void* d_out, int out_size, void* d_ws, size_t ws_size,
                              hipStream_t stream) {
    const float* x  = (const float*)d_in[0];
    const int*   ei = (const int*)d_in[1];   // int32 edge_index [2, E]
    const float* W1 = (const float*)d_in[2];
    const float* b1 = (const float*)d_in[3];
    const float* W2 = (const float*)d_in[4];
    const float* b2 = (const float*)d_in[5];

    const int n = in_sizes[0] / 512;
    const int E = in_sizes[1] / 2;
    const int* src = ei;
    const int* dst = ei + E;

    // workspace layout (floats): deg[n] | dinv[n] | hs[16n] | agg1[16n] | hs2[2n] | agg2[2n]
    float* ws   = (float*)d_ws;
    float* degf = ws;
    float* dinv = ws + (size_t)n;
    float* hs   = ws + (size_t)2 * n;
    float* agg1 = ws + (size_t)18 * n;
    float* hs2  = ws + (size_t)34 * n;
    float* agg2 = ws + (size_t)36 * n;

    hipMemsetAsync(degf, 0, (size_t)n * sizeof(float), stream);

    k_deg<<<(E + THREADS - 1) / THREADS, THREADS, 0, stream>>>(dst, degf, E);
    k_dinv<<<(n + THREADS - 1) / THREADS, THREADS, 0, stream>>>(degf, dinv, n);
    k_gemm1<<<(n + 63) / 64, THREADS, 0, stream>>>(x, W1, dinv, hs, agg1, n);
    k_scatter1<<<(4 * E + THREADS - 1) / THREADS, THREADS, 0, stream>>>(src, dst, hs, agg1, E);
    k_layer2<<<(n + THREADS - 1) / THREADS, THREADS, 0, stream>>>(agg1, dinv, b1, W2, hs2, agg2, n);
    k_scatter2<<<(E + THREADS - 1) / THREADS, THREADS, 0, stream>>>(src, dst, hs2, agg2, E);
    k_final<<<(n + THREADS - 1) / THREADS, THREADS, 0, stream>>>(agg2, dinv, b2, (float*)d_out, n);
}

// Round 6
// 900.018 us; speedup vs baseline: 1.6882x; 1.6882x over previous
//
#include <hip/hip_runtime.h>
#include <math.h>

#define THREADS 256

// ================= CSR build =================
__global__ __launch_bounds__(THREADS) void k_count(const int* __restrict__ dst,
                                                   int* __restrict__ deg, int E) {
    int e = blockIdx.x * THREADS + threadIdx.x;
    if (e < E) atomicAdd(&deg[dst[e]], 1);
}

// scan1: per-block (1024 elems) exclusive scan of deg -> cursor, block total -> bsum
__global__ __launch_bounds__(THREADS) void k_scan1(const int* __restrict__ deg,
                                                   int* __restrict__ cursor,
                                                   int* __restrict__ bsum, int n) {
    __shared__ int sh[THREADS];
    const int t = threadIdx.x;
    const int base = blockIdx.x * 1024 + t * 4;
    int v0 = 0, v1 = 0, v2 = 0, v3 = 0;
    if (base + 0 < n) v0 = deg[base + 0];
    if (base + 1 < n) v1 = deg[base + 1];
    if (base + 2 < n) v2 = deg[base + 2];
    if (base + 3 < n) v3 = deg[base + 3];
    int p = v0 + v1 + v2 + v3;
    sh[t] = p;
    __syncthreads();
    for (int off = 1; off < THREADS; off <<= 1) {
        int val = (t >= off) ? sh[t - off] : 0;
        __syncthreads();
        sh[t] += val;
        __syncthreads();
    }
    int ex = sh[t] - p;  // exclusive prefix within block
    if (t == THREADS - 1) bsum[blockIdx.x] = sh[t];
    if (base + 0 < n) cursor[base + 0] = ex;
    if (base + 1 < n) cursor[base + 1] = ex + v0;
    if (base + 2 < n) cursor[base + 2] = ex + v0 + v1;
    if (base + 3 < n) cursor[base + 3] = ex + v0 + v1 + v2;
}

// scan2: single block, exclusive scan of nb block sums in place (nb <= 1024)
__global__ __launch_bounds__(THREADS) void k_scan2(int* __restrict__ bsum, int nb) {
    __shared__ int sh[THREADS];
    const int t = threadIdx.x;
    const int base = t * 4;
    int v0 = 0, v1 = 0, v2 = 0, v3 = 0;
    if (base + 0 < nb) v0 = bsum[base + 0];
    if (base + 1 < nb) v1 = bsum[base + 1];
    if (base + 2 < nb) v2 = bsum[base + 2];
    if (base + 3 < nb) v3 = bsum[base + 3];
    int p = v0 + v1 + v2 + v3;
    sh[t] = p;
    __syncthreads();
    for (int off = 1; off < THREADS; off <<= 1) {
        int val = (t >= off) ? sh[t - off] : 0;
        __syncthreads();
        sh[t] += val;
        __syncthreads();
    }
    int ex = sh[t] - p;
    if (base + 0 < nb) bsum[base + 0] = ex;
    if (base + 1 < nb) bsum[base + 1] = ex + v0;
    if (base + 2 < nb) bsum[base + 2] = ex + v0 + v1;
    if (base + 3 < nb) bsum[base + 3] = ex + v0 + v1 + v2;
}

// scan3: add block offsets; also compute dinv = rsqrt(deg+1)
__global__ __launch_bounds__(THREADS) void k_scan3(int* __restrict__ cursor,
                                                   const int* __restrict__ bsum,
                                                   const int* __restrict__ deg,
                                                   float* __restrict__ dinv, int n) {
    const int off = bsum[blockIdx.x];
    const int base = blockIdx.x * 1024 + threadIdx.x * 4;
#pragma unroll
    for (int q = 0; q < 4; ++q) {
        int i = base + q;
        if (i < n) {
            cursor[i] += off;
            dinv[i] = rsqrtf((float)deg[i] + 1.0f);
        }
    }
}

// fill: bucket src by dst. After this, cursor[v] == end offset of node v.
__global__ __launch_bounds__(THREADS) void k_fill(const int* __restrict__ src,
                                                  const int* __restrict__ dst,
                                                  int* __restrict__ cursor,
                                                  int* __restrict__ col, int E) {
    int e = blockIdx.x * THREADS + threadIdx.x;
    if (e >= E) return;
    int d = dst[e];
    int pos = atomicAdd(&cursor[d], 1);
    col[pos] = src[e];
}

// ================= layer-1 GEMM: hs = (x @ W1) * dinv =================
// 16 lanes per row-group, 4 rows per group, W1^T staged in LDS (padded to 516).
__global__ __launch_bounds__(THREADS) void k_gemm1(const float* __restrict__ x,
                                                   const float* __restrict__ W1,
                                                   const float* __restrict__ dinv,
                                                   float* __restrict__ hs, int n) {
    __shared__ float wt[16][516];
    for (int idx = threadIdx.x; idx < 512 * 16; idx += THREADS) {
        int k = idx >> 4, j = idx & 15;
        wt[j][k] = W1[idx];
    }
    __syncthreads();

    const int g = threadIdx.x >> 4;
    const int j = threadIdx.x & 15;
    const int base = blockIdx.x * 64 + g * 4;
    if (base >= n && blockIdx.x * 64 >= n) return;

    int r0 = min(base + 0, n - 1);
    int r1 = min(base + 1, n - 1);
    int r2 = min(base + 2, n - 1);
    int r3 = min(base + 3, n - 1);

    const float4* __restrict__ x0 = (const float4*)(x + (size_t)r0 * 512);
    const float4* __restrict__ x1 = (const float4*)(x + (size_t)r1 * 512);
    const float4* __restrict__ x2 = (const float4*)(x + (size_t)r2 * 512);
    const float4* __restrict__ x3 = (const float4*)(x + (size_t)r3 * 512);
    const float4* __restrict__ w4 = (const float4*)(&wt[j][0]);

    float a0 = 0.f, a1 = 0.f, a2 = 0.f, a3 = 0.f;
#pragma unroll 4
    for (int k4 = 0; k4 < 128; ++k4) {
        float4 w = w4[k4];
        float4 v;
        v = x0[k4];
        a0 = fmaf(v.x, w.x, a0); a0 = fmaf(v.y, w.y, a0);
        a0 = fmaf(v.z, w.z, a0); a0 = fmaf(v.w, w.w, a0);
        v = x1[k4];
        a1 = fmaf(v.x, w.x, a1); a1 = fmaf(v.y, w.y, a1);
        a1 = fmaf(v.z, w.z, a1); a1 = fmaf(v.w, w.w, a1);
        v = x2[k4];
        a2 = fmaf(v.x, w.x, a2); a2 = fmaf(v.y, w.y, a2);
        a2 = fmaf(v.z, w.z, a2); a2 = fmaf(v.w, w.w, a2);
        v = x3[k4];
        a3 = fmaf(v.x, w.x, a3); a3 = fmaf(v.y, w.y, a3);
        a3 = fmaf(v.z, w.z, a3); a3 = fmaf(v.w, w.w, a3);
    }

    if (base + 0 < n) hs[(size_t)r0 * 16 + j] = a0 * dinv[r0];
    if (base + 1 < n) hs[(size_t)r1 * 16 + j] = a1 * dinv[r1];
    if (base + 2 < n) hs[(size_t)r2 * 16 + j] = a2 * dinv[r2];
    if (base + 3 < n) hs[(size_t)r3 * 16 + j] = a3 * dinv[r3];
}

// ====== gather layer-1 + fused layer-2 matmul: hs2 = (relu(dinv*agg1+b1) @ W2) * dinv ======
// 16 lanes per node (lane j owns feature j). agg1 = hs[v] + sum over incoming edges.
__global__ __launch_bounds__(THREADS) void k_gather1_l2(const int* __restrict__ col,
                                                        const int* __restrict__ cursor,
                                                        const int* __restrict__ deg,
                                                        const float* __restrict__ hs,
                                                        const float* __restrict__ dinv,
                                                        const float* __restrict__ b1,
                                                        const float* __restrict__ W2,
                                                        float* __restrict__ hs2, int n) {
    int t = blockIdx.x * THREADS + threadIdx.x;
    int v = t >> 4, j = t & 15;
    if (v >= n) return;
    const int end = cursor[v];            // cursor holds end offsets after k_fill
    const int start = end - deg[v];
    float acc = hs[(size_t)v * 16 + j];   // self-loop
    for (int e = start; e < end; ++e) {
        int s = col[e];                   // broadcast across the 16-lane group
        acc += hs[(size_t)s * 16 + j];
    }
    const float dv = dinv[v];
    float h1 = fmaxf(fmaf(dv, acc, b1[j]), 0.0f);
    float c0 = h1 * W2[j * 2 + 0];
    float c1 = h1 * W2[j * 2 + 1];
#pragma unroll
    for (int off = 8; off; off >>= 1) {
        c0 += __shfl_xor(c0, off, 16);
        c1 += __shfl_xor(c1, off, 16);
    }
    if (j == 0) ((float2*)hs2)[v] = make_float2(c0 * dv, c1 * dv);
}

// ====== gather layer-2 + final sigmoid: out = sigmoid(dinv*(hs2[v]+sum hs2[src]) + b2) ======
// 8 lanes per node, strided edge loop, shuffle reduce.
__global__ __launch_bounds__(THREADS) void k_gather2_final(const int* __restrict__ col,
                                                           const int* __restrict__ cursor,
                                                           const int* __restrict__ deg,
                                                           const float* __restrict__ hs2,
                                                           const float* __restrict__ dinv,
                                                           const float* __restrict__ b2,
                                                           float* __restrict__ out, int n) {
    int t = blockIdx.x * THREADS + threadIdx.x;
    int v = t >> 3, j = t & 7;
    if (v >= n) return;
    const int end = cursor[v];
    const int start = end - deg[v];
    float a0 = 0.f, a1 = 0.f;
    for (int e = start + j; e < end; e += 8) {
        int s = col[e];
        float2 p = ((const float2*)hs2)[s];
        a0 += p.x;
        a1 += p.y;
    }
#pragma unroll
    for (int off = 4; off; off >>= 1) {
        a0 += __shfl_xor(a0, off, 8);
        a1 += __shfl_xor(a1, off, 8);
    }
    if (j == 0) {
        float dv = dinv[v];
        float2 self = ((const float2*)hs2)[v];
        float z0 = fmaf(dv, self.x + a0, b2[0]);
        float z1 = fmaf(dv, self.y + a1, b2[1]);
        float o0 = 1.0f / (1.0f + expf(-z0));
        float o1 = 1.0f / (1.0f + expf(-z1));
        ((float2*)out)[v] = make_float2(o0, o1);
    }
}

extern "C" void kernel_launch(void* const* d_in, const int* in_sizes, int n_in,
                              void* d_out, int out_size, void* d_ws, size_t ws_size,
                              hipStream_t stream) {
    const float* x  = (const float*)d_in[0];
    const int*   ei = (const int*)d_in[1];   // int32 edge_index [2, E]
    const float* W1 = (const float*)d_in[2];
    const float* b1 = (const float*)d_in[3];
    const float* W2 = (const float*)d_in[4];
    const float* b2 = (const float*)d_in[5];

    const int n = in_sizes[0] / 512;
    const int E = in_sizes[1] / 2;
    const int* src = ei;
    const int* dst = ei + E;

    // workspace layout (4B elems):
    // deg[n] | cursor[n] | bsum[1024] | col[E] | dinv[n] | hs[16n] | hs2[2n]
    int*   deg    = (int*)d_ws;
    int*   cursor = deg + n;
    int*   bsum   = cursor + n;
    int*   col    = bsum + 1024;
    float* dinv   = (float*)(col + E);
    float* hs     = dinv + n;
    float* hs2    = hs + (size_t)16 * n;

    const int nb = (n + 1023) / 1024;  // scan blocks (<= 1024)

    hipMemsetAsync(deg, 0, (size_t)n * sizeof(int), stream);

    k_count<<<(E + THREADS - 1) / THREADS, THREADS, 0, stream>>>(dst, deg, E);
    k_scan1<<<nb, THREADS, 0, stream>>>(deg, cursor, bsum, n);
    k_scan2<<<1, THREADS, 0, stream>>>(bsum, nb);
    k_scan3<<<nb, THREADS, 0, stream>>>(cursor, bsum, deg, dinv, n);
    k_fill<<<(E + THREADS - 1) / THREADS, THREADS, 0, stream>>>(src, dst, cursor, col, E);
    k_gemm1<<<(n + 63) / 64, THREADS, 0, stream>>>(x, W1, dinv, hs, n);
    k_gather1_l2<<<((size_t)16 * n + THREADS - 1) / THREADS, THREADS, 0, stream>>>(
        col, cursor, deg, hs, dinv, b1, W2, hs2, n);
    k_gather2_final<<<((size_t)8 * n + THREADS - 1) / THREADS, THREADS, 0, stream>>>(
        col, cursor, deg, hs2, dinv, b2, (float*)d_out, n);
}